// Round 1
// baseline (296.965 us; speedup 1.0000x reference)
//
#include <hip/hip_runtime.h>

#define N_PTS 131072
#define K_CODES 1024
#define DIM 64
#define DECAYF 0.99f
#define OMDF 0.01f
#define EPSF 1e-5f

// ---- d_out layout (float elements, reference return order) ----
#define OUT_ZQ      0                  // [N, D]
#define OUT_LOSS    8388608            // scalar
#define OUT_IDX     8388609            // [N] (indices as floats)
#define OUT_NEWEMB  8519681            // [K, D]
#define OUT_NEWCS   8585217            // [K]
#define OUT_NEWEMA  8586241            // [K, D]

// ---- ws layout (float elements) ----
// zero region: [0, WS_ZERO_END)
#define WS_C8       0                  // 8*K floats
#define WS_ACNT     8192               // 16 ints
#define WS_LOSS     8208               // 16 floats
#define WS_EMBSUM   8224               // K*D floats (atomic accumulator)
#define WS_ZERO_END 73760
#define WS_ENORM    73760              // K
#define WS_CUR8     74784              // 8*K ints
#define WS_CS       82976              // K
#define WS_AMBIG    84000              // N ints
#define WS_ORDER    215072             // N ints (packed code<<17|row)
#define WS_E2       346144             // K*128 bf16 (32768 float slots); byte off %16==0

typedef __attribute__((ext_vector_type(8))) short bf16x8;
typedef __attribute__((ext_vector_type(4))) float f32x4;

static __device__ inline short f2bf(float f) {
    unsigned u = __float_as_uint(f);
    unsigned r = (u + 0x7fffu + ((u >> 16) & 1u)) >> 16;   // RNE
    return (short)r;
}
static __device__ inline float bf2f(short h) {
    return __uint_as_float(((unsigned)(unsigned short)h) << 16);
}

// E -> E2 = bf16 hi/lo split of (-2E), K-layout [hi(64) | lo(64)]; enorm fp32.
// 4 threads per code (16 dims each) -> coalesced float4 loads, quad-shfl norm.
__global__ __launch_bounds__(256) void econv_kernel(const float* __restrict__ E,
                                                    short* __restrict__ E2,
                                                    float* __restrict__ enorm) {
    int tid = threadIdx.x;
    int code = blockIdx.x * 64 + (tid >> 2);
    int seg = tid & 3;
    const float4* e4 = (const float4*)(E + (size_t)code * DIM + seg * 16);
    float4 v0 = e4[0], v1 = e4[1], v2 = e4[2], v3 = e4[3];
    float f[16];
    f[0]=v0.x; f[1]=v0.y; f[2]=v0.z; f[3]=v0.w;
    f[4]=v1.x; f[5]=v1.y; f[6]=v1.z; f[7]=v1.w;
    f[8]=v2.x; f[9]=v2.y; f[10]=v2.z; f[11]=v2.w;
    f[12]=v3.x; f[13]=v3.y; f[14]=v3.z; f[15]=v3.w;
    float s = 0.f;
#pragma unroll
    for (int j = 0; j < 16; ++j) s += f[j] * f[j];
    s += __shfl_xor(s, 1);
    s += __shfl_xor(s, 2);
    short hi[16], lo[16];
#pragma unroll
    for (int j = 0; j < 16; ++j) {
        float m = -2.f * f[j];
        short h = f2bf(m);
        hi[j] = h;
        lo[j] = f2bf(m - bf2f(h));
    }
    short* o = E2 + (size_t)code * 128 + seg * 16;
    *(bf16x8*)(o)      = *(bf16x8*)(hi);
    *(bf16x8*)(o + 8)  = *(bf16x8*)(hi + 8);
    *(bf16x8*)(o + 64) = *(bf16x8*)(lo);
    *(bf16x8*)(o + 72) = *(bf16x8*)(lo + 8);
    if (seg == 0) enorm[code] = s;
}

// 1024 blocks x 256 thr; wave = 32 rows (2 m-tiles) x all 1024 codes (64
// n-tiles). 3-product Ootomo split bf16 GEMM; enorm rides in the MFMA C
// operand (acc init = en). Top-2 is index-free: code packed into the low
// 10 mantissa bits of the score; s1 = min, s2 = fmed3. Rows whose top-2
// gap < dynamic tau (covers pack+split error) -> exact fp32 rescue.
// Also: commitment-loss partial (znorm + s1) for non-ambiguous rows.
// 32 rows/wave (not 64) so the grid gives 4 blocks/CU = 16 waves/CU:
// the 2-blocks/CU version stalled both pipes at 21% occupancy.
__global__ __launch_bounds__(256) void argmin_mfma(const float* __restrict__ z,
                                                   const short* __restrict__ E2,
                                                   const float* __restrict__ enorm,
                                                   float* __restrict__ out_idx_f,
                                                   float* __restrict__ counts8,
                                                   int* __restrict__ ambig_cnt,
                                                   int* __restrict__ ambig,
                                                   float* __restrict__ loss_ws) {
    int tid = threadIdx.x;
    int w = tid >> 6, lane = tid & 63;
    int c = lane & 15, q = lane >> 4;
    int mbase = blockIdx.x * 128 + w * 32;

    // A-frags, hi/lo split. A[m=lane&15][k=q*8+j]. Also exact znorm per
    // loaded row (row = mbase + t*16 + c).
    bf16x8 a[2][4];   // [t][p]: p= 0:hi d0-31, 1:hi d32-63, 2:lo d0-31, 3:lo d32-63
    float znorm_t[2];
#pragma unroll
    for (int t = 0; t < 2; ++t) {
        const float* zp = z + (size_t)(mbase + t * 16 + c) * DIM;
        const float4* z4a = (const float4*)(zp + q * 8);
        const float4* z4b = (const float4*)(zp + 32 + q * 8);
        float f[16];
        float4 v0 = z4a[0], v1 = z4a[1], v2 = z4b[0], v3 = z4b[1];
        f[0]=v0.x; f[1]=v0.y; f[2]=v0.z; f[3]=v0.w;
        f[4]=v1.x; f[5]=v1.y; f[6]=v1.z; f[7]=v1.w;
        f[8]=v2.x; f[9]=v2.y; f[10]=v2.z; f[11]=v2.w;
        f[12]=v3.x; f[13]=v3.y; f[14]=v3.z; f[15]=v3.w;
        float zn = 0.f;
#pragma unroll
        for (int j = 0; j < 16; ++j) zn += f[j] * f[j];
        // each quad holds 16 of the row's 64 dims; sum across the 4 quads
#pragma unroll
        for (int off = 16; off < 64; off <<= 1) zn += __shfl_xor(zn, off);
        znorm_t[t] = zn;
#pragma unroll
        for (int j = 0; j < 8; ++j) {
            short h0 = f2bf(f[j]);
            a[t][0][j] = h0;
            a[t][2][j] = f2bf(f[j] - bf2f(h0));
            short h1 = f2bf(f[8 + j]);
            a[t][1][j] = h1;
            a[t][3][j] = f2bf(f[8 + j] - bf2f(h1));
        }
    }

    float s1[8], s2[8];
#pragma unroll
    for (int idx = 0; idx < 8; ++idx) { s1[idx] = INFINITY; s2[idx] = INFINITY; }

    unsigned vcode = (unsigned)c;
#pragma unroll 2
    for (int tile = 0; tile < 64; ++tile) {
        const bf16x8* bp = (const bf16x8*)E2 + ((size_t)(tile * 16 + c) * 16) + q;
        bf16x8 bh0 = bp[0], bh1 = bp[4], bl0 = bp[8], bl1 = bp[12];
        float en = enorm[tile * 16 + c];
#pragma unroll
        for (int t = 0; t < 2; ++t) {
            f32x4 acc = {en, en, en, en};
            acc = __builtin_amdgcn_mfma_f32_16x16x32_bf16(a[t][0], bl0, acc, 0, 0, 0); // zh.el
            acc = __builtin_amdgcn_mfma_f32_16x16x32_bf16(a[t][1], bl1, acc, 0, 0, 0);
            acc = __builtin_amdgcn_mfma_f32_16x16x32_bf16(a[t][2], bh0, acc, 0, 0, 0); // zl.eh
            acc = __builtin_amdgcn_mfma_f32_16x16x32_bf16(a[t][3], bh1, acc, 0, 0, 0);
            acc = __builtin_amdgcn_mfma_f32_16x16x32_bf16(a[t][0], bh0, acc, 0, 0, 0); // zh.eh
            acc = __builtin_amdgcn_mfma_f32_16x16x32_bf16(a[t][1], bh1, acc, 0, 0, 0);
#pragma unroll
            for (int i = 0; i < 4; ++i) {
                // pack code into low 10 bits (bfi pattern), then min/med3
                float sp = __uint_as_float(
                    (__float_as_uint(acc[i]) & 0xFFFFFC00u) | vcode);
                int idx = t * 4 + i;
                float ns2 = __builtin_amdgcn_fmed3f(s1[idx], s2[idx], sp);
                s1[idx] = fminf(s1[idx], sp);
                s2[idx] = ns2;
            }
        }
        vcode += 16;
    }

    // merge the 16 col-lanes per quad (packed values carry the index)
#pragma unroll
    for (int off = 1; off < 16; off <<= 1) {
#pragma unroll
        for (int idx = 0; idx < 8; ++idx) {
            float os1 = __shfl_xor(s1[idx], off);
            float os2 = __shfl_xor(s2[idx], off);
            float ns1 = fminf(s1[idx], os1);
            s2[idx] = fminf(fmaxf(s1[idx], os1), fminf(s2[idx], os2));
            s1[idx] = ns1;
        }
    }

    // znorm transport: lane (q*16 + r) holds znorm for row mbase + t*16 + r
    float znr[8];
#pragma unroll
    for (int t = 0; t < 2; ++t)
#pragma unroll
        for (int i = 0; i < 4; ++i)
            znr[t * 4 + i] = __shfl(znorm_t[t], (q << 4) | (q * 4 + i), 64);

    __shared__ float lred[16];
    float lsum = 0.f;
    if (c == 0) {
#pragma unroll
        for (int idx = 0; idx < 8; ++idx) {
            int t = idx >> 2, i = idx & 3;
            int row = mbase + t * 16 + q * 4 + i;
            unsigned b1 = __float_as_uint(s1[idx]);
            int code = (int)(b1 & 1023u);
            out_idx_f[row] = (float)code;
            float s1v = __uint_as_float(b1 & 0xFFFFFC00u);
            float gap = s2[idx] - s1[idx];
            float tau = 0.008f + 8e-4f * (fabsf(s1[idx]) + fabsf(s2[idx]));
            if (gap >= tau) {
                atomicAdd(&counts8[(((unsigned)row >> 8) & 7) * K_CODES + code], 1.0f);
                lsum += znr[idx] + s1v;
            } else {
                int p = atomicAdd(ambig_cnt, 1);
                ambig[p] = row;
            }
        }
        lred[w * 4 + q] = lsum;
    }
    __syncthreads();
    if (tid == 0) {
        float tot = 0.f;
#pragma unroll
        for (int i = 0; i < 16; ++i) tot += lred[i];
        atomicAdd(loss_ws, tot);
    }
}

// Wave per 2 ambiguous rows: exact fp32 rescore over all K codes; also adds
// the exact loss contribution for those rows.
__global__ __launch_bounds__(256) void rescue_kernel(const float* __restrict__ z,
                                                     const float* __restrict__ E,
                                                     const float* __restrict__ enorm,
                                                     const int* __restrict__ ambig_cnt,
                                                     const int* __restrict__ ambig,
                                                     float* __restrict__ out_idx_f,
                                                     float* __restrict__ counts8,
                                                     float* __restrict__ loss_ws) {
    int lane = threadIdx.x & 63;
    int wave = (blockIdx.x * 256 + threadIdx.x) >> 6;
    int nw = gridDim.x * 4;
    int cnt = *ambig_cnt;
    for (int a = 2 * wave; a < cnt; a += 2 * nw) {
        int row0 = ambig[a];
        bool two = (a + 1) < cnt;
        int row1 = two ? ambig[a + 1] : row0;
        const float4* zp0 = (const float4*)(z + (size_t)row0 * DIM);
        const float4* zp1 = (const float4*)(z + (size_t)row1 * DIM);
        float4 zr0[16], zr1[16];
        float zn0 = 0.f, zn1 = 0.f;
#pragma unroll
        for (int i = 0; i < 16; ++i) {
            float4 u = zp0[i], v = zp1[i];
            zr0[i] = u; zr1[i] = v;
            zn0 += u.x * u.x + u.y * u.y + u.z * u.z + u.w * u.w;
            zn1 += v.x * v.x + v.y * v.y + v.z * v.z + v.w * v.w;
        }
        float best0 = INFINITY, best1 = INFINITY;
        int bi0 = 0, bi1 = 0;
        for (int j = 0; j < 16; ++j) {
            int code = j * 64 + lane;
            const float4* ep = (const float4*)(E + (size_t)code * DIM);
            float a0 = 0.f, a1 = 0.f, a2 = 0.f, a3 = 0.f;
            float c0 = 0.f, c1 = 0.f, c2 = 0.f, c3 = 0.f;
#pragma unroll
            for (int i = 0; i < 16; ++i) {
                float4 ev = ep[i];
                a0 += zr0[i].x * ev.x; a1 += zr0[i].y * ev.y;
                a2 += zr0[i].z * ev.z; a3 += zr0[i].w * ev.w;
                c0 += zr1[i].x * ev.x; c1 += zr1[i].y * ev.y;
                c2 += zr1[i].z * ev.z; c3 += zr1[i].w * ev.w;
            }
            float en = enorm[code];
            float s0 = en - 2.f * ((a0 + a1) + (a2 + a3));
            float s1 = en - 2.f * ((c0 + c1) + (c2 + c3));
            if (s0 < best0) { best0 = s0; bi0 = code; }
            if (s1 < best1) { best1 = s1; bi1 = code; }
        }
#pragma unroll
        for (int off = 1; off < 64; off <<= 1) {
            float ob = __shfl_xor(best0, off);
            int oi = __shfl_xor(bi0, off);
            if (ob < best0 || (ob == best0 && oi < bi0)) { best0 = ob; bi0 = oi; }
            float ob1 = __shfl_xor(best1, off);
            int oi1 = __shfl_xor(bi1, off);
            if (ob1 < best1 || (ob1 == best1 && oi1 < bi1)) { best1 = ob1; bi1 = oi1; }
        }
        if (lane == 0) {
            out_idx_f[row0] = (float)bi0;
            atomicAdd(&counts8[(((unsigned)row0 >> 8) & 7) * K_CODES + bi0], 1.0f);
            float ladd = zn0 + best0;
            if (two) {
                out_idx_f[row1] = (float)bi1;
                atomicAdd(&counts8[(((unsigned)row1 >> 8) & 7) * K_CODES + bi1], 1.0f);
                ladd += zn1 + best1;
            }
            atomicAdd(loss_ws, ladd);
        }
    }
}

// counts8 -> ncs, n, cs, sharded cursors. Shfl-scan, 2 barriers.
__global__ __launch_bounds__(1024) void scan_kernel(const float* __restrict__ cluster_size,
                                                    const float* __restrict__ counts8,
                                                    float* __restrict__ ncs_out,
                                                    float* __restrict__ cs_ws,
                                                    int* __restrict__ cursor8) {
    int k = threadIdx.x;
    int lane = k & 63, wv = k >> 6;
    float c8[8];
    float cnt = 0.f;
#pragma unroll
    for (int s = 0; s < 8; ++s) { c8[s] = counts8[s * K_CODES + k]; cnt += c8[s]; }
    float ncs = cluster_size[k] * DECAYF + OMDF * cnt;
    ncs_out[k] = ncs;

    // wave-inclusive scan of int counts
    int v = (int)cnt;
    int vs = v;
#pragma unroll
    for (int off = 1; off < 64; off <<= 1) {
        int o = __shfl_up(vs, off, 64);
        if (lane >= off) vs += o;
    }
    // wave total of ncs (for n)
    float fs = ncs;
#pragma unroll
    for (int off = 1; off < 64; off <<= 1) fs += __shfl_xor(fs, off);

    __shared__ int wtot[16];
    __shared__ float ftot[16];
    __shared__ float nsh;
    if (lane == 63) wtot[wv] = vs;
    if (lane == 0) ftot[wv] = fs;
    __syncthreads();
    if (k == 0) {
        int run = 0; float fn = 0.f;
#pragma unroll
        for (int i = 0; i < 16; ++i) {
            int t = wtot[i]; wtot[i] = run; run += t;
            fn += ftot[i];
        }
        nsh = fn;
    }
    __syncthreads();
    float n = nsh;
    cs_ws[k] = (ncs + EPSF) / (n + (float)K_CODES * EPSF) * n;

    int excl = vs - v + wtot[wv];
    int run = excl;
#pragma unroll
    for (int s = 0; s < 8; ++s) { cursor8[s * K_CODES + k] = run; run += (int)c8[s]; }
}

// Fused scatter + z_q gather-write (indices final after rescue; cursors final
// after scan). One idx pass feeds both the order scatter and the z_q store.
__global__ __launch_bounds__(256) void scatter_zq_kernel(const float* __restrict__ E,
                                                         const float* __restrict__ idx_f,
                                                         int* __restrict__ cursor8,
                                                         int* __restrict__ order,
                                                         float* __restrict__ zq) {
    __shared__ int s_k[256];
    int tid = threadIdx.x;
    int rbase = blockIdx.x * 256;
    int row = rbase + tid;
    int k = (int)idx_f[row];
    s_k[tid] = k;
    int shard = ((unsigned)row >> 8) & 7;
    int p = atomicAdd(&cursor8[shard * K_CODES + k], 1);
    order[p] = (k << 17) | row;
    __syncthreads();
    size_t ebase = (size_t)rbase * DIM;
#pragma unroll 4
    for (int it = 0; it < 64; ++it) {
        int le = it * 256 + tid;
        int rl = le >> 6, d = le & 63;
        zq[ebase + le] = E[(size_t)s_k[rl] * DIM + d];
    }
}

// Work-partitioned segment sum: each wave owns 64 entries of the sorted
// order array; lane = dim; run-length accumulate, flush per code-run.
__global__ __launch_bounds__(256) void segsum_kernel(const float* __restrict__ z,
                                                     const int* __restrict__ order,
                                                     float* __restrict__ embsum) {
    int lane = threadIdx.x & 63;
    int w = threadIdx.x >> 6;
    int wave = blockIdx.x * 4 + w;
    int base = wave * 64;

    int my = order[base + lane];

    int cur = __shfl(my, 0, 64) >> 17;
    float sum = 0.f;
#pragma unroll 8
    for (int i = 0; i < 64; ++i) {
        int p = __shfl(my, i, 64);
        int row = p & 0x1FFFF;
        int code = p >> 17;
        float v = z[(size_t)row * DIM + lane];
        if (code != cur) {
            atomicAdd(&embsum[(size_t)cur * DIM + lane], sum);
            sum = 0.f;
            cur = code;
        }
        sum += v;
    }
    atomicAdd(&embsum[(size_t)cur * DIM + lane], sum);
}

// EMA epilogue over [K, D] + loss finalize (block 0).
__global__ __launch_bounds__(256) void ema2_kernel(const float* __restrict__ ema,
                                                   const float* __restrict__ embsum,
                                                   const float* __restrict__ cs_ws,
                                                   const float* __restrict__ loss_ws,
                                                   float* __restrict__ newema_out,
                                                   float* __restrict__ newemb_out,
                                                   float* __restrict__ loss_out) {
    int i = blockIdx.x * 256 + threadIdx.x;
    float nes = ema[i] * DECAYF + OMDF * embsum[i];
    newema_out[i] = nes;
    newemb_out[i] = nes / cs_ws[i >> 6];
    if (i == 0)
        loss_out[0] = loss_ws[0] * (1.0f / ((float)N_PTS * (float)DIM));
}

extern "C" void kernel_launch(void* const* d_in, const int* in_sizes, int n_in,
                              void* d_out, int out_size, void* d_ws, size_t ws_size,
                              hipStream_t stream) {
    const float* z            = (const float*)d_in[0];
    const float* E            = (const float*)d_in[1];
    const float* cluster_size = (const float*)d_in[2];
    const float* ema          = (const float*)d_in[3];
    float* out = (float*)d_out;
    float* ws  = (float*)d_ws;

    // zero counts8 + ambig_cnt + loss + embsum accumulator
    hipMemsetAsync(ws, 0, (size_t)WS_ZERO_END * sizeof(float), stream);

    econv_kernel<<<K_CODES / 64, 256, 0, stream>>>(E, (short*)(ws + WS_E2), ws + WS_ENORM);

    argmin_mfma<<<N_PTS / 128, 256, 0, stream>>>(z, (const short*)(ws + WS_E2),
                                                 ws + WS_ENORM,
                                                 out + OUT_IDX,
                                                 ws + WS_C8,
                                                 (int*)(ws + WS_ACNT),
                                                 (int*)(ws + WS_AMBIG),
                                                 ws + WS_LOSS);

    rescue_kernel<<<512, 256, 0, stream>>>(z, E, ws + WS_ENORM,
                                           (const int*)(ws + WS_ACNT),
                                           (const int*)(ws + WS_AMBIG),
                                           out + OUT_IDX,
                                           ws + WS_C8,
                                           ws + WS_LOSS);

    scan_kernel<<<1, 1024, 0, stream>>>(cluster_size, ws + WS_C8,
                                        out + OUT_NEWCS, ws + WS_CS,
                                        (int*)(ws + WS_CUR8));

    scatter_zq_kernel<<<N_PTS / 256, 256, 0, stream>>>(E, out + OUT_IDX,
                                                       (int*)(ws + WS_CUR8),
                                                       (int*)(ws + WS_ORDER),
                                                       out + OUT_ZQ);

    segsum_kernel<<<N_PTS / 256, 256, 0, stream>>>(z,
                                                   (const int*)(ws + WS_ORDER),
                                                   ws + WS_EMBSUM);

    ema2_kernel<<<K_CODES * DIM / 256, 256, 0, stream>>>(ema, ws + WS_EMBSUM,
                                                         ws + WS_CS,
                                                         ws + WS_LOSS,
                                                         out + OUT_NEWEMA,
                                                         out + OUT_NEWEMB,
                                                         out + OUT_LOSS);
}

// Round 2
// 243.603 us; speedup vs baseline: 1.2191x; 1.2191x over previous
//
#include <hip/hip_runtime.h>

#define N_PTS 131072
#define K_CODES 1024
#define DIM 64
#define DECAYF 0.99f
#define OMDF 0.01f
#define EPSF 1e-5f

// ---- d_out layout (float elements, reference return order) ----
#define OUT_ZQ      0                  // [N, D]
#define OUT_LOSS    8388608            // scalar
#define OUT_IDX     8388609            // [N] (indices as floats)
#define OUT_NEWEMB  8519681            // [K, D]
#define OUT_NEWCS   8585217            // [K]
#define OUT_NEWEMA  8586241            // [K, D]

// ---- ws layout (float elements) ----
// zero region: [0, WS_ZERO_END)
#define WS_C8       0                  // 8*K floats
#define WS_ACNT     8192               // 16 ints
#define WS_LOSS     8208               // 16 floats
#define WS_EMBSUM   8224               // K*D floats (atomic accumulator)
#define WS_ZERO_END 73760
#define WS_ENORM    73760              // K
#define WS_CUR8     74784              // 8*K ints
#define WS_CS       82976              // K
#define WS_AMBIG    84000              // N ints
#define WS_ORDER    215072             // N ints (packed code<<17|row)
#define WS_E2       346144             // K*128 bf16 (32768 float slots); byte off %16==0

typedef __attribute__((ext_vector_type(8))) short bf16x8;
typedef __attribute__((ext_vector_type(4))) float f32x4;

static __device__ inline short f2bf(float f) {
    unsigned u = __float_as_uint(f);
    unsigned r = (u + 0x7fffu + ((u >> 16) & 1u)) >> 16;   // RNE
    return (short)r;
}
static __device__ inline float bf2f(short h) {
    return __uint_as_float(((unsigned)(unsigned short)h) << 16);
}

// E -> E2 = bf16 hi/lo split of (-2E), K-layout [hi(64) | lo(64)]; enorm fp32.
// 4 threads per code (16 dims each) -> coalesced float4 loads, quad-shfl norm.
__global__ __launch_bounds__(256) void econv_kernel(const float* __restrict__ E,
                                                    short* __restrict__ E2,
                                                    float* __restrict__ enorm) {
    int tid = threadIdx.x;
    int code = blockIdx.x * 64 + (tid >> 2);
    int seg = tid & 3;
    const float4* e4 = (const float4*)(E + (size_t)code * DIM + seg * 16);
    float4 v0 = e4[0], v1 = e4[1], v2 = e4[2], v3 = e4[3];
    float f[16];
    f[0]=v0.x; f[1]=v0.y; f[2]=v0.z; f[3]=v0.w;
    f[4]=v1.x; f[5]=v1.y; f[6]=v1.z; f[7]=v1.w;
    f[8]=v2.x; f[9]=v2.y; f[10]=v2.z; f[11]=v2.w;
    f[12]=v3.x; f[13]=v3.y; f[14]=v3.z; f[15]=v3.w;
    float s = 0.f;
#pragma unroll
    for (int j = 0; j < 16; ++j) s += f[j] * f[j];
    s += __shfl_xor(s, 1);
    s += __shfl_xor(s, 2);
    short hi[16], lo[16];
#pragma unroll
    for (int j = 0; j < 16; ++j) {
        float m = -2.f * f[j];
        short h = f2bf(m);
        hi[j] = h;
        lo[j] = f2bf(m - bf2f(h));
    }
    short* o = E2 + (size_t)code * 128 + seg * 16;
    *(bf16x8*)(o)      = *(bf16x8*)(hi);
    *(bf16x8*)(o + 8)  = *(bf16x8*)(hi + 8);
    *(bf16x8*)(o + 64) = *(bf16x8*)(lo);
    *(bf16x8*)(o + 72) = *(bf16x8*)(lo + 8);
    if (seg == 0) enorm[code] = s;
}

// 512 blocks x 256 thr; wave = 64 rows (4 m-tiles) x all 1024 codes (64
// n-tiles). 3-product Ootomo split bf16 GEMM; enorm rides in the MFMA C
// operand (acc init = en). Top-2 is index-free: code packed into the low
// 10 mantissa bits of the score; s1 = min, s2 = fmed3. Rows whose top-2
// gap < dynamic tau (covers pack+split error) -> exact fp32 rescue.
// Also: commitment-loss partial (znorm + s1) for non-ambiguous rows.
//
// Lesson from the 32-rows/wave experiment: stall time scales with wave
// count (per-wave B-stream VMEM cost), NOT with occupancy — so keep 64
// rows/wave and instead hide the per-tile L2 latency with an explicit
// 4-deep register pipeline for the B slots (load tile T+4 ~350cy before
// use). Slots are 4 NAMED register sets (no runtime indexing -> no
// scratch).
#define LOADSLOT(S, T) do {                                                  \
    int tt_ = (T) < 63 ? (T) : 63;                                           \
    const bf16x8* bp_ = (const bf16x8*)E2 + ((size_t)((tt_ << 4) + c) << 4) + q; \
    S##h0 = bp_[0]; S##h1 = bp_[4]; S##l0 = bp_[8]; S##l1 = bp_[12];         \
    S##en = enorm[(tt_ << 4) + c];                                           \
} while (0)

#define COMPUTE(S, TILE) do {                                                \
    unsigned vc_ = ((unsigned)(TILE) << 4) | (unsigned)c;                    \
    _Pragma("unroll")                                                        \
    for (int t = 0; t < 4; ++t) {                                            \
        f32x4 acc = {S##en, S##en, S##en, S##en};                            \
        acc = __builtin_amdgcn_mfma_f32_16x16x32_bf16(a[t][0], S##l0, acc, 0, 0, 0); \
        acc = __builtin_amdgcn_mfma_f32_16x16x32_bf16(a[t][1], S##l1, acc, 0, 0, 0); \
        acc = __builtin_amdgcn_mfma_f32_16x16x32_bf16(a[t][2], S##h0, acc, 0, 0, 0); \
        acc = __builtin_amdgcn_mfma_f32_16x16x32_bf16(a[t][3], S##h1, acc, 0, 0, 0); \
        acc = __builtin_amdgcn_mfma_f32_16x16x32_bf16(a[t][0], S##h0, acc, 0, 0, 0); \
        acc = __builtin_amdgcn_mfma_f32_16x16x32_bf16(a[t][1], S##h1, acc, 0, 0, 0); \
        _Pragma("unroll")                                                    \
        for (int i = 0; i < 4; ++i) {                                        \
            float sp = __uint_as_float(                                      \
                (__float_as_uint(acc[i]) & 0xFFFFFC00u) | vc_);              \
            int idx = t * 4 + i;                                             \
            float ns2 = __builtin_amdgcn_fmed3f(s1[idx], s2[idx], sp);       \
            s1[idx] = fminf(s1[idx], sp);                                    \
            s2[idx] = ns2;                                                   \
        }                                                                    \
    }                                                                        \
} while (0)

__global__ __launch_bounds__(256, 2) void argmin_mfma(const float* __restrict__ z,
                                                      const short* __restrict__ E2,
                                                      const float* __restrict__ enorm,
                                                      float* __restrict__ out_idx_f,
                                                      float* __restrict__ counts8,
                                                      int* __restrict__ ambig_cnt,
                                                      int* __restrict__ ambig,
                                                      float* __restrict__ loss_ws) {
    int tid = threadIdx.x;
    int w = tid >> 6, lane = tid & 63;
    int c = lane & 15, q = lane >> 4;
    int mbase = blockIdx.x * 256 + w * 64;

    // A-frags, hi/lo split. A[m=lane&15][k=q*8+j]. Also exact znorm per
    // loaded row (row = mbase + t*16 + c).
    bf16x8 a[4][4];   // [t][p]: p= 0:hi d0-31, 1:hi d32-63, 2:lo d0-31, 3:lo d32-63
    float znorm_t[4];
#pragma unroll
    for (int t = 0; t < 4; ++t) {
        const float* zp = z + (size_t)(mbase + t * 16 + c) * DIM;
        const float4* z4a = (const float4*)(zp + q * 8);
        const float4* z4b = (const float4*)(zp + 32 + q * 8);
        float f[16];
        float4 v0 = z4a[0], v1 = z4a[1], v2 = z4b[0], v3 = z4b[1];
        f[0]=v0.x; f[1]=v0.y; f[2]=v0.z; f[3]=v0.w;
        f[4]=v1.x; f[5]=v1.y; f[6]=v1.z; f[7]=v1.w;
        f[8]=v2.x; f[9]=v2.y; f[10]=v2.z; f[11]=v2.w;
        f[12]=v3.x; f[13]=v3.y; f[14]=v3.z; f[15]=v3.w;
        float zn = 0.f;
#pragma unroll
        for (int j = 0; j < 16; ++j) zn += f[j] * f[j];
        // each quad holds 16 of the row's 64 dims; sum across the 4 quads
#pragma unroll
        for (int off = 16; off < 64; off <<= 1) zn += __shfl_xor(zn, off);
        znorm_t[t] = zn;
#pragma unroll
        for (int j = 0; j < 8; ++j) {
            short h0 = f2bf(f[j]);
            a[t][0][j] = h0;
            a[t][2][j] = f2bf(f[j] - bf2f(h0));
            short h1 = f2bf(f[8 + j]);
            a[t][1][j] = h1;
            a[t][3][j] = f2bf(f[8 + j] - bf2f(h1));
        }
    }

    float s1[16], s2[16];
#pragma unroll
    for (int idx = 0; idx < 16; ++idx) { s1[idx] = INFINITY; s2[idx] = INFINITY; }

    // 4-deep B pipeline: named slots, statically unrolled rotation.
    bf16x8 p0_h0, p0_h1, p0_l0, p0_l1; float p0_en;
    bf16x8 p1_h0, p1_h1, p1_l0, p1_l1; float p1_en;
    bf16x8 p2_h0, p2_h1, p2_l0, p2_l1; float p2_en;
    bf16x8 p3_h0, p3_h1, p3_l0, p3_l1; float p3_en;

    LOADSLOT(p0_, 0);
    LOADSLOT(p1_, 1);
    LOADSLOT(p2_, 2);
    LOADSLOT(p3_, 3);

    for (int tile = 0; tile < 64; tile += 4) {
        COMPUTE(p0_, tile + 0); LOADSLOT(p0_, tile + 4);
        COMPUTE(p1_, tile + 1); LOADSLOT(p1_, tile + 5);
        COMPUTE(p2_, tile + 2); LOADSLOT(p2_, tile + 6);
        COMPUTE(p3_, tile + 3); LOADSLOT(p3_, tile + 7);
    }

    // merge the 16 col-lanes per quad (packed values carry the index)
#pragma unroll
    for (int off = 1; off < 16; off <<= 1) {
#pragma unroll
        for (int idx = 0; idx < 16; ++idx) {
            float os1 = __shfl_xor(s1[idx], off);
            float os2 = __shfl_xor(s2[idx], off);
            float ns1 = fminf(s1[idx], os1);
            s2[idx] = fminf(fmaxf(s1[idx], os1), fminf(s2[idx], os2));
            s1[idx] = ns1;
        }
    }

    // znorm transport: lane (q*16 + r) holds znorm for row mbase + t*16 + r
    float znr[16];
#pragma unroll
    for (int t = 0; t < 4; ++t)
#pragma unroll
        for (int i = 0; i < 4; ++i)
            znr[t * 4 + i] = __shfl(znorm_t[t], (q << 4) | (q * 4 + i), 64);

    __shared__ float lred[16];
    float lsum = 0.f;
    if (c == 0) {
#pragma unroll
        for (int idx = 0; idx < 16; ++idx) {
            int t = idx >> 2, i = idx & 3;
            int row = mbase + t * 16 + q * 4 + i;
            unsigned b1 = __float_as_uint(s1[idx]);
            int code = (int)(b1 & 1023u);
            out_idx_f[row] = (float)code;
            float s1v = __uint_as_float(b1 & 0xFFFFFC00u);
            float gap = s2[idx] - s1[idx];
            float tau = 0.008f + 8e-4f * (fabsf(s1[idx]) + fabsf(s2[idx]));
            if (gap >= tau) {
                atomicAdd(&counts8[(((unsigned)row >> 8) & 7) * K_CODES + code], 1.0f);
                lsum += znr[idx] + s1v;
            } else {
                int p = atomicAdd(ambig_cnt, 1);
                ambig[p] = row;
            }
        }
        lred[w * 4 + q] = lsum;
    }
    __syncthreads();
    if (tid == 0) {
        float tot = 0.f;
#pragma unroll
        for (int i = 0; i < 16; ++i) tot += lred[i];
        atomicAdd(loss_ws, tot);
    }
}

// Wave per 2 ambiguous rows: exact fp32 rescore over all K codes; also adds
// the exact loss contribution for those rows.
__global__ __launch_bounds__(256) void rescue_kernel(const float* __restrict__ z,
                                                     const float* __restrict__ E,
                                                     const float* __restrict__ enorm,
                                                     const int* __restrict__ ambig_cnt,
                                                     const int* __restrict__ ambig,
                                                     float* __restrict__ out_idx_f,
                                                     float* __restrict__ counts8,
                                                     float* __restrict__ loss_ws) {
    int lane = threadIdx.x & 63;
    int wave = (blockIdx.x * 256 + threadIdx.x) >> 6;
    int nw = gridDim.x * 4;
    int cnt = *ambig_cnt;
    for (int a = 2 * wave; a < cnt; a += 2 * nw) {
        int row0 = ambig[a];
        bool two = (a + 1) < cnt;
        int row1 = two ? ambig[a + 1] : row0;
        const float4* zp0 = (const float4*)(z + (size_t)row0 * DIM);
        const float4* zp1 = (const float4*)(z + (size_t)row1 * DIM);
        float4 zr0[16], zr1[16];
        float zn0 = 0.f, zn1 = 0.f;
#pragma unroll
        for (int i = 0; i < 16; ++i) {
            float4 u = zp0[i], v = zp1[i];
            zr0[i] = u; zr1[i] = v;
            zn0 += u.x * u.x + u.y * u.y + u.z * u.z + u.w * u.w;
            zn1 += v.x * v.x + v.y * v.y + v.z * v.z + v.w * v.w;
        }
        float best0 = INFINITY, best1 = INFINITY;
        int bi0 = 0, bi1 = 0;
        for (int j = 0; j < 16; ++j) {
            int code = j * 64 + lane;
            const float4* ep = (const float4*)(E + (size_t)code * DIM);
            float a0 = 0.f, a1 = 0.f, a2 = 0.f, a3 = 0.f;
            float c0 = 0.f, c1 = 0.f, c2 = 0.f, c3 = 0.f;
#pragma unroll
            for (int i = 0; i < 16; ++i) {
                float4 ev = ep[i];
                a0 += zr0[i].x * ev.x; a1 += zr0[i].y * ev.y;
                a2 += zr0[i].z * ev.z; a3 += zr0[i].w * ev.w;
                c0 += zr1[i].x * ev.x; c1 += zr1[i].y * ev.y;
                c2 += zr1[i].z * ev.z; c3 += zr1[i].w * ev.w;
            }
            float en = enorm[code];
            float s0 = en - 2.f * ((a0 + a1) + (a2 + a3));
            float s1 = en - 2.f * ((c0 + c1) + (c2 + c3));
            if (s0 < best0) { best0 = s0; bi0 = code; }
            if (s1 < best1) { best1 = s1; bi1 = code; }
        }
#pragma unroll
        for (int off = 1; off < 64; off <<= 1) {
            float ob = __shfl_xor(best0, off);
            int oi = __shfl_xor(bi0, off);
            if (ob < best0 || (ob == best0 && oi < bi0)) { best0 = ob; bi0 = oi; }
            float ob1 = __shfl_xor(best1, off);
            int oi1 = __shfl_xor(bi1, off);
            if (ob1 < best1 || (ob1 == best1 && oi1 < bi1)) { best1 = ob1; bi1 = oi1; }
        }
        if (lane == 0) {
            out_idx_f[row0] = (float)bi0;
            atomicAdd(&counts8[(((unsigned)row0 >> 8) & 7) * K_CODES + bi0], 1.0f);
            float ladd = zn0 + best0;
            if (two) {
                out_idx_f[row1] = (float)bi1;
                atomicAdd(&counts8[(((unsigned)row1 >> 8) & 7) * K_CODES + bi1], 1.0f);
                ladd += zn1 + best1;
            }
            atomicAdd(loss_ws, ladd);
        }
    }
}

// counts8 -> ncs, n, cs, sharded cursors. Shfl-scan, 2 barriers.
__global__ __launch_bounds__(1024) void scan_kernel(const float* __restrict__ cluster_size,
                                                    const float* __restrict__ counts8,
                                                    float* __restrict__ ncs_out,
                                                    float* __restrict__ cs_ws,
                                                    int* __restrict__ cursor8) {
    int k = threadIdx.x;
    int lane = k & 63, wv = k >> 6;
    float c8[8];
    float cnt = 0.f;
#pragma unroll
    for (int s = 0; s < 8; ++s) { c8[s] = counts8[s * K_CODES + k]; cnt += c8[s]; }
    float ncs = cluster_size[k] * DECAYF + OMDF * cnt;
    ncs_out[k] = ncs;

    // wave-inclusive scan of int counts
    int v = (int)cnt;
    int vs = v;
#pragma unroll
    for (int off = 1; off < 64; off <<= 1) {
        int o = __shfl_up(vs, off, 64);
        if (lane >= off) vs += o;
    }
    // wave total of ncs (for n)
    float fs = ncs;
#pragma unroll
    for (int off = 1; off < 64; off <<= 1) fs += __shfl_xor(fs, off);

    __shared__ int wtot[16];
    __shared__ float ftot[16];
    __shared__ float nsh;
    if (lane == 63) wtot[wv] = vs;
    if (lane == 0) ftot[wv] = fs;
    __syncthreads();
    if (k == 0) {
        int run = 0; float fn = 0.f;
#pragma unroll
        for (int i = 0; i < 16; ++i) {
            int t = wtot[i]; wtot[i] = run; run += t;
            fn += ftot[i];
        }
        nsh = fn;
    }
    __syncthreads();
    float n = nsh;
    cs_ws[k] = (ncs + EPSF) / (n + (float)K_CODES * EPSF) * n;

    int excl = vs - v + wtot[wv];
    int run = excl;
#pragma unroll
    for (int s = 0; s < 8; ++s) { cursor8[s * K_CODES + k] = run; run += (int)c8[s]; }
}

// Fused scatter + z_q gather-write (indices final after rescue; cursors final
// after scan). One idx pass feeds both the order scatter and the z_q store.
__global__ __launch_bounds__(256) void scatter_zq_kernel(const float* __restrict__ E,
                                                         const float* __restrict__ idx_f,
                                                         int* __restrict__ cursor8,
                                                         int* __restrict__ order,
                                                         float* __restrict__ zq) {
    __shared__ int s_k[256];
    int tid = threadIdx.x;
    int rbase = blockIdx.x * 256;
    int row = rbase + tid;
    int k = (int)idx_f[row];
    s_k[tid] = k;
    int shard = ((unsigned)row >> 8) & 7;
    int p = atomicAdd(&cursor8[shard * K_CODES + k], 1);
    order[p] = (k << 17) | row;
    __syncthreads();
    size_t ebase = (size_t)rbase * DIM;
#pragma unroll 4
    for (int it = 0; it < 64; ++it) {
        int le = it * 256 + tid;
        int rl = le >> 6, d = le & 63;
        zq[ebase + le] = E[(size_t)s_k[rl] * DIM + d];
    }
}

// Work-partitioned segment sum: each wave owns 64 entries of the sorted
// order array; lane = dim; run-length accumulate, flush per code-run.
__global__ __launch_bounds__(256) void segsum_kernel(const float* __restrict__ z,
                                                     const int* __restrict__ order,
                                                     float* __restrict__ embsum) {
    int lane = threadIdx.x & 63;
    int w = threadIdx.x >> 6;
    int wave = blockIdx.x * 4 + w;
    int base = wave * 64;

    int my = order[base + lane];

    int cur = __shfl(my, 0, 64) >> 17;
    float sum = 0.f;
#pragma unroll 8
    for (int i = 0; i < 64; ++i) {
        int p = __shfl(my, i, 64);
        int row = p & 0x1FFFF;
        int code = p >> 17;
        float v = z[(size_t)row * DIM + lane];
        if (code != cur) {
            atomicAdd(&embsum[(size_t)cur * DIM + lane], sum);
            sum = 0.f;
            cur = code;
        }
        sum += v;
    }
    atomicAdd(&embsum[(size_t)cur * DIM + lane], sum);
}

// EMA epilogue over [K, D] + loss finalize (block 0).
__global__ __launch_bounds__(256) void ema2_kernel(const float* __restrict__ ema,
                                                   const float* __restrict__ embsum,
                                                   const float* __restrict__ cs_ws,
                                                   const float* __restrict__ loss_ws,
                                                   float* __restrict__ newema_out,
                                                   float* __restrict__ newemb_out,
                                                   float* __restrict__ loss_out) {
    int i = blockIdx.x * 256 + threadIdx.x;
    float nes = ema[i] * DECAYF + OMDF * embsum[i];
    newema_out[i] = nes;
    newemb_out[i] = nes / cs_ws[i >> 6];
    if (i == 0)
        loss_out[0] = loss_ws[0] * (1.0f / ((float)N_PTS * (float)DIM));
}

extern "C" void kernel_launch(void* const* d_in, const int* in_sizes, int n_in,
                              void* d_out, int out_size, void* d_ws, size_t ws_size,
                              hipStream_t stream) {
    const float* z            = (const float*)d_in[0];
    const float* E            = (const float*)d_in[1];
    const float* cluster_size = (const float*)d_in[2];
    const float* ema          = (const float*)d_in[3];
    float* out = (float*)d_out;
    float* ws  = (float*)d_ws;

    // zero counts8 + ambig_cnt + loss + embsum accumulator
    hipMemsetAsync(ws, 0, (size_t)WS_ZERO_END * sizeof(float), stream);

    econv_kernel<<<K_CODES / 64, 256, 0, stream>>>(E, (short*)(ws + WS_E2), ws + WS_ENORM);

    argmin_mfma<<<N_PTS / 256, 256, 0, stream>>>(z, (const short*)(ws + WS_E2),
                                                 ws + WS_ENORM,
                                                 out + OUT_IDX,
                                                 ws + WS_C8,
                                                 (int*)(ws + WS_ACNT),
                                                 (int*)(ws + WS_AMBIG),
                                                 ws + WS_LOSS);

    rescue_kernel<<<512, 256, 0, stream>>>(z, E, ws + WS_ENORM,
                                           (const int*)(ws + WS_ACNT),
                                           (const int*)(ws + WS_AMBIG),
                                           out + OUT_IDX,
                                           ws + WS_C8,
                                           ws + WS_LOSS);

    scan_kernel<<<1, 1024, 0, stream>>>(cluster_size, ws + WS_C8,
                                        out + OUT_NEWCS, ws + WS_CS,
                                        (int*)(ws + WS_CUR8));

    scatter_zq_kernel<<<N_PTS / 256, 256, 0, stream>>>(E, out + OUT_IDX,
                                                       (int*)(ws + WS_CUR8),
                                                       (int*)(ws + WS_ORDER),
                                                       out + OUT_ZQ);

    segsum_kernel<<<N_PTS / 256, 256, 0, stream>>>(z,
                                                   (const int*)(ws + WS_ORDER),
                                                   ws + WS_EMBSUM);

    ema2_kernel<<<K_CODES * DIM / 256, 256, 0, stream>>>(ema, ws + WS_EMBSUM,
                                                         ws + WS_CS,
                                                         ws + WS_LOSS,
                                                         out + OUT_NEWEMA,
                                                         out + OUT_NEWEMB,
                                                         out + OUT_LOSS);
}